// Round 10
// baseline (317.479 us; speedup 1.0000x reference)
//
#include <hip/hip_runtime.h>

// MultiHeadAttention B=16 N=1024 E=768 H=8 D=96 — fp16 MFMA pipeline.
// ws layout (130.6 MB total):
//   WT   [3072][768] fp16 : rows 0-2303 = (Wq|Wk|Wv)^T, rows 2304-3071 = Wo^T
//   bias [2304] f32
//   xh   [16384][768] fp16
//   QKV  [16384][2304] fp16 (cols: 0-767 Q, 768-1535 K, 1536-2303 V; head h at h*96)
//   Oh   [16384][768] fp16 (attention output, pre-projection)

typedef _Float16 half8 __attribute__((ext_vector_type(8)));
typedef __fp16 fp16x2 __attribute__((ext_vector_type(2)));
typedef float f32x4 __attribute__((ext_vector_type(4)));
typedef float f32x16 __attribute__((ext_vector_type(16)));

__device__ __forceinline__ void gload_lds16(const void* g, void* l) {
  __builtin_amdgcn_global_load_lds((const __attribute__((address_space(1))) void*)g,
                                   (__attribute__((address_space(3))) void*)l, 16, 0, 0);
}

// ---------------- converts ----------------

__global__ __launch_bounds__(256) void conv_x_kernel(const float* __restrict__ x,
                                                     _Float16* __restrict__ xh) {
  long i = ((long)blockIdx.x * 256 + threadIdx.x) * 8;
  float4 a = *(const float4*)(x + i);
  float4 b = *(const float4*)(x + i + 4);
  half8 o;
  o[0] = (_Float16)a.x; o[1] = (_Float16)a.y; o[2] = (_Float16)a.z; o[3] = (_Float16)a.w;
  o[4] = (_Float16)b.x; o[5] = (_Float16)b.y; o[6] = (_Float16)b.z; o[7] = (_Float16)b.w;
  *(half8*)(xh + i) = o;
}

__global__ __launch_bounds__(256) void transpose_cvt_kernel(
    const float* __restrict__ W0, const float* __restrict__ W1,
    const float* __restrict__ W2, const float* __restrict__ W3,
    _Float16* __restrict__ WT) {
  __shared__ float tile[32][33];
  int z = blockIdx.z;
  const float* W = (z == 0) ? W0 : (z == 1) ? W1 : (z == 2) ? W2 : W3;
  int k0 = blockIdx.y * 32, n0 = blockIdx.x * 32;
  int tx = threadIdx.x, ty = threadIdx.y;
#pragma unroll
  for (int j = ty; j < 32; j += 8)
    tile[j][tx] = W[(size_t)(k0 + j) * 768 + n0 + tx];
  __syncthreads();
  _Float16* dst = WT + (size_t)z * 768 * 768;
#pragma unroll
  for (int j = ty; j < 32; j += 8)
    dst[(size_t)(n0 + j) * 768 + k0 + tx] = (_Float16)tile[tx][j];
}

__global__ __launch_bounds__(256) void conv_bias_kernel(const float* __restrict__ bq,
                                                        const float* __restrict__ bk,
                                                        const float* __restrict__ bv,
                                                        float* __restrict__ bias) {
  int i = blockIdx.x * 256 + threadIdx.x;
  if (i >= 2304) return;
  bias[i] = (i < 768) ? bq[i] : (i < 1536) ? bk[i - 768] : bv[i - 1536];
}

// ---------------- GEMM: C[M][ldc] = A[M][K] * Bt[N][K]^T + bias ----------------
// m97 structure: 128x128 tile, BK=32, 4 waves, global_load_lds width=16,
// 2 barriers per K-step, XCD-swizzled 1D grid. Grids 2304/768: exact rounds.

template <int OUT_F16>
__global__ __launch_bounds__(256) void gemm_nt_kernel(
    const _Float16* __restrict__ A, const _Float16* __restrict__ Bt,
    const float* __restrict__ bias, void* __restrict__ C,
    int M, int N, int K, int ldc) {
  __shared__ _Float16 As[128 * 32];
  __shared__ _Float16 Bs[128 * 32];
  int nbx = N >> 7;
  int nwg = gridDim.x;
  int wg = blockIdx.x;
  int cpx = nwg >> 3;                       // nwg % 8 == 0 guaranteed by launch
  int swz = (wg & 7) * cpx + (wg >> 3);     // XCD-aware bijective swizzle
  int bx = swz % nbx, by = swz / nbx;
  int m0 = by * 128, n0 = bx * 128;
  int t = threadIdx.x, l = t & 63, w = t >> 6;
  int lg = l >> 4, lr = l & 15;
  int wr = w >> 1, wc = w & 1;
  f32x4 acc[4][4] = {};

  for (int k0 = 0; k0 < K; k0 += 32) {
    __syncthreads();  // previous compute done before overwrite
#pragma unroll
    for (int j = 0; j < 2; ++j) {
      int slot = j * 256 + t;
      gload_lds16(A + (size_t)(m0 + (slot >> 2)) * K + k0 + (slot & 3) * 8, &As[slot * 8]);
    }
#pragma unroll
    for (int j = 0; j < 2; ++j) {
      int slot = j * 256 + t;
      gload_lds16(Bt + (size_t)(n0 + (slot >> 2)) * K + k0 + (slot & 3) * 8, &Bs[slot * 8]);
    }
    __syncthreads();  // drains vmcnt -> tiles ready
    half8 af[4], bf[4];
#pragma unroll
    for (int r = 0; r < 4; ++r) af[r] = *(const half8*)&As[(wr * 64 + r * 16 + lr) * 32 + lg * 8];
#pragma unroll
    for (int c = 0; c < 4; ++c) bf[c] = *(const half8*)&Bs[(wc * 64 + c * 16 + lr) * 32 + lg * 8];
#pragma unroll
    for (int r = 0; r < 4; ++r)
#pragma unroll
      for (int c = 0; c < 4; ++c)
        acc[r][c] = __builtin_amdgcn_mfma_f32_16x16x32_f16(af[r], bf[c], acc[r][c], 0, 0, 0);
  }

#pragma unroll
  for (int r = 0; r < 4; ++r)
#pragma unroll
    for (int c = 0; c < 4; ++c) {
      int col = n0 + wc * 64 + c * 16 + lr;
      float bb = bias[col];
#pragma unroll
      for (int i = 0; i < 4; ++i) {
        int row = m0 + wr * 64 + r * 16 + lg * 4 + i;  // D: col=lane&15, row=4*(lane>>4)+i
        float v = acc[r][c][i] + bb;
        if (OUT_F16)
          ((_Float16*)C)[(size_t)row * ldc + col] = (_Float16)v;
        else
          ((float*)C)[(size_t)row * ldc + col] = v;
      }
    }
}

// ---------------- flash attention: 32x32 MFMA, in-register P ----------------
// Grid 512 (= 2/CU x 256 CU, ONE tail-free round), 512 thr = 8 waves; wave owns
// 32 q rows (QBLK=256). KVBLK=64, double-buffered, LDS 48KB.
// KF fragment-major (conflict-free b128); VF scatter layout with d-XOR swizzle.
// P in registers: exp2 with CONSTANT vector indices (rule #20), pack to dwords,
// keep/send via single hi-select per word, lane<->lane^32 via shfl_xor(32).
// Staging jobs (wave-uniform kinds): all thr K slot t; thr<256 K slot 512+t,
// thr>=256 V unit t-256; thr<128 V unit 256+t.
// Q pre-scaled by LOG2E; defer-max THR=11.5; O /= (l_run*sqrt(768)).

__global__ __launch_bounds__(512, 4) void attn_kernel(const _Float16* __restrict__ QKV,
                                                      _Float16* __restrict__ Oh) {
  int hw = blockIdx.x;
  int lin = (hw & 7) * 64 + (hw >> 3);    // XCD-chunked: 64 consecutive per XCD
  int bh = lin >> 2, qt = lin & 3;
  int b = bh >> 3, h = bh & 7;
  int t = threadIdx.x, w = t >> 6, l = t & 63;
  int lr = l & 31, hi = l >> 5;

  __shared__ __align__(16) char KF[2][12288];
  __shared__ __align__(16) _Float16 VF[2][96 * 64];

  const _Float16* Qb = QKV + (size_t)b * 1024 * 2304 + h * 96;
  const _Float16* Kb = Qb + 768;
  const _Float16* Vb = Qb + 1536;

  // Q fragments (B-operand): lane holds Q[q = qt*256+w*32+lr][d = c*16+hi*8 .. +7]
  half8 qf[6];
  {
    int qrow = qt * 256 + w * 32 + lr;
    const _Float16 s = (_Float16)1.4426950408889634f;  // LOG2E folded into Q
#pragma unroll
    for (int c = 0; c < 6; ++c) {
      qf[c] = *(const half8*)&Qb[(size_t)qrow * 2304 + c * 16 + hi * 8];
#pragma unroll
      for (int e = 0; e < 8; ++e) qf[c][e] = qf[c][e] * s;
    }
  }

  // ---- hoisted staging offsets ----
  // K slot s (0..767): frag f=s>>6, lane=s&63, sb=f/6, c=f%6
  auto kslot = [](int s, int& src, int& dst) {
    int f = s >> 6, lane = s & 63;
    int sb = f / 6, c = f - sb * 6;
    src = (sb * 32 + (lane & 31)) * 2304 + c * 16 + ((lane >> 5) & 1) * 8;
    dst = s * 16;
  };
  // V unit u (0..383): kv pair + 8-d chunk reg-transpose scatter
  auto vunit = [](int u, int& src, int* dst) {
    int kvp = u / 12, mm = u % 12;
    src = 2 * kvp * 2304 + mm * 8;
#pragma unroll
    for (int e = 0; e < 8; ++e) {
      int d = mm * 8 + e;
      int sw = ((d & 7) ^ ((d >> 3) & 7)) << 3;
      dst[e] = d * 64 + ((2 * kvp) ^ sw);
    }
  };

  int k1_src, k1_dst;
  kslot(t, k1_src, k1_dst);
  bool j2K = t < 256;                 // wave-uniform (waves 0-3)
  int k2_src = 0, k2_dst = 0, v2_src = 0, v2_dst[8] = {};
  if (j2K) kslot(512 + t, k2_src, k2_dst);
  else     vunit(t - 256, v2_src, v2_dst);
  bool j3 = t < 128;                  // wave-uniform (waves 0-1)
  int v3_src = 0, v3_dst[8] = {};
  if (j3) vunit(256 + t, v3_src, v3_dst);

  auto vscatter = [&](const _Float16* vp, _Float16* vf, const int* dst) {
    half8 v0 = *(const half8*)vp;
    half8 v1 = *(const half8*)(vp + 2304);
#pragma unroll
    for (int e = 0; e < 8; ++e) {
      union { _Float16 h2[2]; unsigned u32; } pk;
      pk.h2[0] = v0[e]; pk.h2[1] = v1[e];
      *(unsigned*)&vf[dst[e]] = pk.u32;
    }
  };

  auto stage = [&](int kv0, int bi) {
    size_t goff = (size_t)kv0 * 2304;
    gload_lds16(Kb + goff + k1_src, &KF[bi][k1_dst]);
    if (j2K) gload_lds16(Kb + goff + k2_src, &KF[bi][k2_dst]);
    else     vscatter(Vb + goff + v2_src, VF[bi], v2_dst);
    if (j3)  vscatter(Vb + goff + v3_src, VF[bi], v3_dst);
  };

  float m_run = -3.0e38f, l_run = 0.f;
  f32x16 oa[3] = {};  // O: col d = dt*32+lr, row q = (reg&3)+8*(reg>>2)+4*hi

  stage(0, 0);

  for (int tile = 0; tile < 16; ++tile) {
    int bi = tile & 1;
    __syncthreads();  // stage(tile) resident; compute(tile-1) done
    if (tile + 1 < 16) stage((tile + 1) * 64, bi ^ 1);

    // --- QK^T: S^T sub-tiles (kv subtile sb of 32) x full d=96
    f32x16 sA[2] = {};
#pragma unroll
    for (int sb = 0; sb < 2; ++sb)
#pragma unroll
      for (int c = 0; c < 6; ++c) {
        half8 kf = *(const half8*)(KF[bi] + (sb * 6 + c) * 1024 + l * 16);
        sA[sb] = __builtin_amdgcn_mfma_f32_32x32x16_f16(kf, qf[c], sA[sb], 0, 0, 0);
      }

    // --- softmax (log2 domain); lane owns q = lr; 32 vals in-lane + partner
    float tmax = -3.0e38f;
#pragma unroll
    for (int sb = 0; sb < 2; ++sb)
#pragma unroll
      for (int r = 0; r < 16; ++r) tmax = fmaxf(tmax, sA[sb][r]);
    tmax = fmaxf(tmax, __shfl_xor(tmax, 32, 64));

    if (!__all(tmax <= m_run + 11.5f)) {   // defer-max
      float m_new = fmaxf(m_run, tmax);
      float scale = __builtin_exp2f(m_run - m_new);
#pragma unroll
      for (int r = 0; r < 16; ++r) {
        float sr = __shfl(scale, (r & 3) + 8 * (r >> 2) + 4 * hi, 64);
        oa[0][r] *= sr; oa[1][r] *= sr; oa[2][r] *= sr;
      }
      l_run *= scale;
      m_run = m_new;
    }

    // --- P = exp2(S-m) with CONSTANT indices; pack; keep/send via hi-select.
    unsigned keep[8], send[8];  // idx = sb*4 + kb*2 + m
    float rs = 0.f;
#pragma unroll
    for (int sb = 0; sb < 2; ++sb) {
      float e[16];
#pragma unroll
      for (int r = 0; r < 16; ++r) {
        e[r] = __builtin_exp2f(sA[sb][r] - m_run);
        rs += e[r];
      }
      unsigned w32[8];
#pragma unroll
      for (int p = 0; p < 4; ++p)
#pragma unroll
        for (int m = 0; m < 2; ++m) {
          union { fp16x2 h2; unsigned u; } pk;
          pk.h2 = __builtin_amdgcn_cvt_pkrtz(e[4 * p + 2 * m], e[4 * p + 2 * m + 1]);
          w32[p * 2 + m] = pk.u;
        }
#pragma unroll
      for (int kb = 0; kb < 2; ++kb)
#pragma unroll
        for (int m = 0; m < 2; ++m) {
          keep[sb * 4 + kb * 2 + m] = hi ? w32[(2 * kb + 1) * 2 + m] : w32[(2 * kb) * 2 + m];
          send[sb * 4 + kb * 2 + m] = hi ? w32[(2 * kb) * 2 + m] : w32[(2 * kb + 1) * 2 + m];
        }
    }
    rs += __shfl_xor(rs, 32, 64);
    l_run += rs;

    unsigned recv[8];
#pragma unroll
    for (int i = 0; i < 8; ++i) recv[i] = __shfl_xor(send[i], 32, 64);

    // --- assemble PV A-frags and multiply against V fragments
#pragma unroll
    for (int kstep = 0; kstep < 4; ++kstep) {
      int base = (kstep >> 1) * 4 + (kstep & 1) * 2;
      union { unsigned u[4]; half8 h8; } pa;
      pa.u[0] = hi ? recv[base + 0] : keep[base + 0];
      pa.u[1] = hi ? recv[base + 1] : keep[base + 1];
      pa.u[2] = hi ? keep[base + 0] : recv[base + 0];
      pa.u[3] = hi ? keep[base + 1] : recv[base + 1];
#pragma unroll
      for (int dt = 0; dt < 3; ++dt) {
        int d = dt * 32 + lr;
        int sw = ((d & 7) ^ ((d >> 3) & 7)) << 3;
        half8 vf = *(const half8*)&VF[bi][d * 64 + ((kstep * 16 + hi * 8) ^ sw)];
        oa[dt] = __builtin_amdgcn_mfma_f32_32x32x16_f16(pa.h8, vf, oa[dt], 0, 0, 0);
      }
    }
  }

  // --- epilogue: O /= (l_run * sqrt(768))
  float inv = 1.0f / (l_run * 27.712812921102035f);
  size_t rbase = (size_t)(b * 1024 + qt * 256 + w * 32) * 768 + h * 96;
#pragma unroll
  for (int r = 0; r < 16; ++r) {
    int q = (r & 3) + 8 * (r >> 2) + 4 * hi;
    float ivr = __shfl(inv, q, 64);
#pragma unroll
    for (int dt = 0; dt < 3; ++dt)
      Oh[rbase + (size_t)q * 768 + dt * 32 + lr] = (_Float16)(oa[dt][r] * ivr);
  }
}

// ---------------- launch ----------------

extern "C" void kernel_launch(void* const* d_in, const int* in_sizes, int n_in,
                              void* d_out, int out_size, void* d_ws, size_t ws_size,
                              hipStream_t stream) {
  const float* x  = (const float*)d_in[0];
  const float* Wq = (const float*)d_in[1];
  const float* bq = (const float*)d_in[2];
  const float* Wk = (const float*)d_in[3];
  const float* bk = (const float*)d_in[4];
  const float* Wv = (const float*)d_in[5];
  const float* bv = (const float*)d_in[6];
  const float* Wo = (const float*)d_in[7];
  const float* bo = (const float*)d_in[8];
  float* out = (float*)d_out;

  char* ws = (char*)d_ws;
  _Float16* WT   = (_Float16*)(ws);                // 4,718,592 B
  float*    bias = (float*)(ws + 4718592);         // 9,216 B (padded to 32K)
  _Float16* xh   = (_Float16*)(ws + 4751360);      // 25,165,824 B
  _Float16* QKV  = (_Float16*)(ws + 29917184);     // 75,497,472 B
  _Float16* Oh   = (_Float16*)(ws + 105414656);    // 25,165,824 B  (total ~130.6 MB)

  conv_x_kernel<<<6144, 256, 0, stream>>>(x, xh);
  transpose_cvt_kernel<<<dim3(24, 24, 4), dim3(32, 8), 0, stream>>>(Wq, Wk, Wv, Wo, WT);
  conv_bias_kernel<<<9, 256, 0, stream>>>(bq, bk, bv, bias);

  // QKV: M=16384, N=2304, K=768 -> grid 128*18 = 2304 (3 exact rounds of 768)
  gemm_nt_kernel<1><<<2304, 256, 0, stream>>>(xh, WT, bias, QKV, 16384, 2304, 768, 2304);

  attn_kernel<<<512, 512, 0, stream>>>(QKV, Oh);

  // out-proj: M=16384, N=768, K=768 -> grid 128*6 = 768 (1 exact round)
  gemm_nt_kernel<0><<<768, 256, 0, stream>>>(Oh, WT + (size_t)2304 * 768, bo, out,
                                             16384, 768, 768, 768);
}

// Round 11
// 232.645 us; speedup vs baseline: 1.3646x; 1.3646x over previous
//
#include <hip/hip_runtime.h>

// MultiHeadAttention B=16 N=1024 E=768 H=8 D=96 — fp16 MFMA pipeline.
// ws layout (130.6 MB total):
//   WT   [3072][768] fp16 : rows 0-2303 = (Wq|Wk|Wv)^T, rows 2304-3071 = Wo^T
//   bias [2304] f32
//   xh   [16384][768] fp16
//   QKV  [16384][2304] fp16 (cols: 0-767 Q, 768-1535 K, 1536-2303 V; head h at h*96)
//   Oh   [16384][768] fp16 (attention output, pre-projection)

typedef _Float16 half8 __attribute__((ext_vector_type(8)));
typedef __fp16 fp16x2 __attribute__((ext_vector_type(2)));
typedef float f32x4 __attribute__((ext_vector_type(4)));
typedef float f32x16 __attribute__((ext_vector_type(16)));

__device__ __forceinline__ void gload_lds16(const void* g, void* l) {
  __builtin_amdgcn_global_load_lds((const __attribute__((address_space(1))) void*)g,
                                   (__attribute__((address_space(3))) void*)l, 16, 0, 0);
}

// ---------------- converts ----------------

__global__ __launch_bounds__(256) void conv_x_kernel(const float* __restrict__ x,
                                                     _Float16* __restrict__ xh) {
  long i = ((long)blockIdx.x * 256 + threadIdx.x) * 8;
  float4 a = *(const float4*)(x + i);
  float4 b = *(const float4*)(x + i + 4);
  half8 o;
  o[0] = (_Float16)a.x; o[1] = (_Float16)a.y; o[2] = (_Float16)a.z; o[3] = (_Float16)a.w;
  o[4] = (_Float16)b.x; o[5] = (_Float16)b.y; o[6] = (_Float16)b.z; o[7] = (_Float16)b.w;
  *(half8*)(xh + i) = o;
}

__global__ __launch_bounds__(256) void transpose_cvt_kernel(
    const float* __restrict__ W0, const float* __restrict__ W1,
    const float* __restrict__ W2, const float* __restrict__ W3,
    _Float16* __restrict__ WT) {
  __shared__ float tile[32][33];
  int z = blockIdx.z;
  const float* W = (z == 0) ? W0 : (z == 1) ? W1 : (z == 2) ? W2 : W3;
  int k0 = blockIdx.y * 32, n0 = blockIdx.x * 32;
  int tx = threadIdx.x, ty = threadIdx.y;
#pragma unroll
  for (int j = ty; j < 32; j += 8)
    tile[j][tx] = W[(size_t)(k0 + j) * 768 + n0 + tx];
  __syncthreads();
  _Float16* dst = WT + (size_t)z * 768 * 768;
#pragma unroll
  for (int j = ty; j < 32; j += 8)
    dst[(size_t)(n0 + j) * 768 + k0 + tx] = (_Float16)tile[tx][j];
}

__global__ __launch_bounds__(256) void conv_bias_kernel(const float* __restrict__ bq,
                                                        const float* __restrict__ bk,
                                                        const float* __restrict__ bv,
                                                        float* __restrict__ bias) {
  int i = blockIdx.x * 256 + threadIdx.x;
  if (i >= 2304) return;
  bias[i] = (i < 768) ? bq[i] : (i < 1536) ? bk[i - 768] : bv[i - 1536];
}

// ---------------- GEMM: C[M][ldc] = A[M][K] * Bt[N][K]^T + bias ----------------
// m97 structure: 128x128 tile, BK=32, 4 waves, global_load_lds width=16,
// 2 barriers per K-step, XCD-swizzled 1D grid. Grids 2304/768: exact rounds.

template <int OUT_F16>
__global__ __launch_bounds__(256) void gemm_nt_kernel(
    const _Float16* __restrict__ A, const _Float16* __restrict__ Bt,
    const float* __restrict__ bias, void* __restrict__ C,
    int M, int N, int K, int ldc) {
  __shared__ _Float16 As[128 * 32];
  __shared__ _Float16 Bs[128 * 32];
  int nbx = N >> 7;
  int nwg = gridDim.x;
  int wg = blockIdx.x;
  int cpx = nwg >> 3;                       // nwg % 8 == 0 guaranteed by launch
  int swz = (wg & 7) * cpx + (wg >> 3);     // XCD-aware bijective swizzle
  int bx = swz % nbx, by = swz / nbx;
  int m0 = by * 128, n0 = bx * 128;
  int t = threadIdx.x, l = t & 63, w = t >> 6;
  int lg = l >> 4, lr = l & 15;
  int wr = w >> 1, wc = w & 1;
  f32x4 acc[4][4] = {};

  for (int k0 = 0; k0 < K; k0 += 32) {
    __syncthreads();  // previous compute done before overwrite
#pragma unroll
    for (int j = 0; j < 2; ++j) {
      int slot = j * 256 + t;
      gload_lds16(A + (size_t)(m0 + (slot >> 2)) * K + k0 + (slot & 3) * 8, &As[slot * 8]);
    }
#pragma unroll
    for (int j = 0; j < 2; ++j) {
      int slot = j * 256 + t;
      gload_lds16(Bt + (size_t)(n0 + (slot >> 2)) * K + k0 + (slot & 3) * 8, &Bs[slot * 8]);
    }
    __syncthreads();  // drains vmcnt -> tiles ready
    half8 af[4], bf[4];
#pragma unroll
    for (int r = 0; r < 4; ++r) af[r] = *(const half8*)&As[(wr * 64 + r * 16 + lr) * 32 + lg * 8];
#pragma unroll
    for (int c = 0; c < 4; ++c) bf[c] = *(const half8*)&Bs[(wc * 64 + c * 16 + lr) * 32 + lg * 8];
#pragma unroll
    for (int r = 0; r < 4; ++r)
#pragma unroll
      for (int c = 0; c < 4; ++c)
        acc[r][c] = __builtin_amdgcn_mfma_f32_16x16x32_f16(af[r], bf[c], acc[r][c], 0, 0, 0);
  }

#pragma unroll
  for (int r = 0; r < 4; ++r)
#pragma unroll
    for (int c = 0; c < 4; ++c) {
      int col = n0 + wc * 64 + c * 16 + lr;
      float bb = bias[col];
#pragma unroll
      for (int i = 0; i < 4; ++i) {
        int row = m0 + wr * 64 + r * 16 + lg * 4 + i;  // D: col=lane&15, row=4*(lane>>4)+i
        float v = acc[r][c][i] + bb;
        if (OUT_F16)
          ((_Float16*)C)[(size_t)row * ldc + col] = (_Float16)v;
        else
          ((float*)C)[(size_t)row * ldc + col] = v;
      }
    }
}

// ---------------- flash attention: 32x32 MFMA, in-register P ----------------
// R8 frame (best known): grid 1024 XCD-chunked, 256 thr = 4 waves, wave owns 32 q
// rows (QBLK=128), KVBLK=64, double-buffered, LDS 48KB, launch_bounds(256,2)
// (NO register squeeze — R9/R10 lesson: caps below ~128 VGPR spill or stall).
// KF fragment-major (conflict-free b128); VF scatter layout with d-XOR swizzle.
// P in registers (rule #20-safe constant indexing), lane<->lane^32 via shfl_xor.
// NEW vs R8:
//  (a) T14 async-STAGE split for V: issue V global loads right after the barrier,
//      scatter-write AFTER compute (vmcnt latency hidden under MFMA phase).
//  (b) row-sum l via MFMA ones-column: lacc = mfma(pa, 1, lacc) — kills 32 adds +
//      shuffles per tile and the epilogue broadcast; lacc rescales with oa.
// Q pre-scaled by LOG2E; defer-max THR=11.5; O /= (l * sqrt(768)).

__global__ __launch_bounds__(256, 2) void attn_kernel(const _Float16* __restrict__ QKV,
                                                      _Float16* __restrict__ Oh) {
  int hw = blockIdx.x;
  int lin = (hw & 7) * 128 + (hw >> 3);   // XCD-chunked
  int bh = lin >> 3, qt = lin & 7;
  int b = bh >> 3, h = bh & 7;
  int t = threadIdx.x, w = t >> 6, l = t & 63;
  int lr = l & 31, hi = l >> 5;

  __shared__ __align__(16) char KF[2][12288];
  __shared__ __align__(16) _Float16 VF[2][96 * 64];

  const _Float16* Qb = QKV + (size_t)b * 1024 * 2304 + h * 96;
  const _Float16* Kb = Qb + 768;
  const _Float16* Vb = Qb + 1536;

  // Q fragments (B-operand): lane holds Q[q = qt*128+w*32+lr][d = c*16+hi*8 .. +7]
  half8 qf[6];
  {
    int qrow = qt * 128 + w * 32 + lr;
    const _Float16 s = (_Float16)1.4426950408889634f;  // LOG2E folded into Q
#pragma unroll
    for (int c = 0; c < 6; ++c) {
      qf[c] = *(const half8*)&Qb[(size_t)qrow * 2304 + c * 16 + hi * 8];
#pragma unroll
      for (int e = 0; e < 8; ++e) qf[c][e] = qf[c][e] * s;
    }
  }

  // ---- hoisted staging offsets ----
  int ks_src[3], ks_dst[3];
#pragma unroll
  for (int j = 0; j < 3; ++j) {
    int s = j * 256 + t;
    int f = s >> 6, lane = s & 63;
    int sb = f / 6, c = f - sb * 6;
    ks_src[j] = (sb * 32 + (lane & 31)) * 2304 + c * 16 + ((lane >> 5) & 1) * 8;
    ks_dst[j] = s * 16;
  }
  bool vact[2];
  int v_src[2], v_dst[2][8];
#pragma unroll
  for (int j = 0; j < 2; ++j) {
    int u = j * 256 + t;
    vact[j] = u < 384;                 // j=0: all; j=1: waves 0-1 only (uniform)
    int kvp = u / 12, mm = u % 12;
    v_src[j] = 2 * kvp * 2304 + mm * 8;
#pragma unroll
    for (int e = 0; e < 8; ++e) {
      int d = mm * 8 + e;
      int sw = ((d & 7) ^ ((d >> 3) & 7)) << 3;
      v_dst[j][e] = d * 64 + ((2 * kvp) ^ sw);
    }
  }

  auto stage_K = [&](int kv0, int bi) {   // fire-and-forget direct-to-LDS
    size_t goff = (size_t)kv0 * 2304;
#pragma unroll
    for (int j = 0; j < 3; ++j)
      gload_lds16(Kb + goff + ks_src[j], &KF[bi][ks_dst[j]]);
  };

  half8 vr0[2], vr1[2];                   // in-flight V tile (T14 split)
  auto loadV = [&](int kv0) {
    size_t goff = (size_t)kv0 * 2304;
#pragma unroll
    for (int j = 0; j < 2; ++j)
      if (vact[j]) {
        const _Float16* vp = Vb + goff + v_src[j];
        vr0[j] = *(const half8*)vp;
        vr1[j] = *(const half8*)(vp + 2304);
      }
  };
  auto writeV = [&](int bi) {             // vmcnt wait lands HERE (after compute)
#pragma unroll
    for (int j = 0; j < 2; ++j)
      if (vact[j]) {
#pragma unroll
        for (int e = 0; e < 8; ++e) {
          union { _Float16 h2[2]; unsigned u32; } pk;
          pk.h2[0] = vr0[j][e]; pk.h2[1] = vr1[j][e];
          *(unsigned*)&VF[bi][v_dst[j][e]] = pk.u32;
        }
      }
  };

  half8 vones;
#pragma unroll
  for (int e = 0; e < 8; ++e) vones[e] = (_Float16)1.0f;

  float m_run = -3.0e38f;
  f32x16 oa[3] = {};   // O: col d = dt*32+lr, row q = (reg&3)+8*(reg>>2)+4*hi
  f32x16 lacc = {};    // row-sum of P (same row mapping), via ones-MFMA

  stage_K(0, 0);
  loadV(0);
  writeV(0);

  for (int tile = 0; tile < 16; ++tile) {
    int bi = tile & 1;
    __syncthreads();  // KF[bi]/VF[bi] ready; compute(tile-1) done
    if (tile + 1 < 16) {
      stage_K((tile + 1) * 64, bi ^ 1);
      loadV((tile + 1) * 64);
      __builtin_amdgcn_sched_barrier(0);  // pin load issue before compute
    }

    // --- QK^T: S^T sub-tiles (kv subtile sb of 32) x full d=96
    f32x16 sA[2] = {};
#pragma unroll
    for (int sb = 0; sb < 2; ++sb)
#pragma unroll
      for (int c = 0; c < 6; ++c) {
        half8 kf = *(const half8*)(KF[bi] + (sb * 6 + c) * 1024 + l * 16);
        sA[sb] = __builtin_amdgcn_mfma_f32_32x32x16_f16(kf, qf[c], sA[sb], 0, 0, 0);
      }

    // --- softmax (log2 domain); lane owns q = lr; 32 vals in-lane + partner
    float tmax = -3.0e38f;
#pragma unroll
    for (int sb = 0; sb < 2; ++sb)
#pragma unroll
      for (int r = 0; r < 16; ++r) tmax = fmaxf(tmax, sA[sb][r]);
    tmax = fmaxf(tmax, __shfl_xor(tmax, 32, 64));

    if (!__all(tmax <= m_run + 11.5f)) {   // defer-max
      float m_new = fmaxf(m_run, tmax);
      float scale = __builtin_exp2f(m_run - m_new);
#pragma unroll
      for (int r = 0; r < 16; ++r) {
        float sr = __shfl(scale, (r & 3) + 8 * (r >> 2) + 4 * hi, 64);
        oa[0][r] *= sr; oa[1][r] *= sr; oa[2][r] *= sr;
        lacc[r] *= sr;
      }
      m_run = m_new;
    }

    // --- P = exp2(S-m) with CONSTANT indices; pack; keep/send via hi-select.
    unsigned keep[8], send[8];  // idx = sb*4 + kb*2 + m
#pragma unroll
    for (int sb = 0; sb < 2; ++sb) {
      float e[16];
#pragma unroll
      for (int r = 0; r < 16; ++r) e[r] = __builtin_exp2f(sA[sb][r] - m_run);
      unsigned w32[8];
#pragma unroll
      for (int p = 0; p < 4; ++p)
#pragma unroll
        for (int m = 0; m < 2; ++m) {
          union { fp16x2 h2; unsigned u; } pk;
          pk.h2 = __builtin_amdgcn_cvt_pkrtz(e[4 * p + 2 * m], e[4 * p + 2 * m + 1]);
          w32[p * 2 + m] = pk.u;
        }
#pragma unroll
      for (int kb = 0; kb < 2; ++kb)
#pragma unroll
        for (int m = 0; m < 2; ++m) {
          keep[sb * 4 + kb * 2 + m] = hi ? w32[(2 * kb + 1) * 2 + m] : w32[(2 * kb) * 2 + m];
          send[sb * 4 + kb * 2 + m] = hi ? w32[(2 * kb) * 2 + m] : w32[(2 * kb + 1) * 2 + m];
        }
    }

    unsigned recv[8];
#pragma unroll
    for (int i = 0; i < 8; ++i) recv[i] = __shfl_xor(send[i], 32, 64);

    // --- assemble PV A-frags; PV + row-sum (ones-column) MFMAs
#pragma unroll
    for (int kstep = 0; kstep < 4; ++kstep) {
      int base = (kstep >> 1) * 4 + (kstep & 1) * 2;
      union { unsigned u[4]; half8 h8; } pa;
      pa.u[0] = hi ? recv[base + 0] : keep[base + 0];
      pa.u[1] = hi ? recv[base + 1] : keep[base + 1];
      pa.u[2] = hi ? keep[base + 0] : recv[base + 0];
      pa.u[3] = hi ? keep[base + 1] : recv[base + 1];
#pragma unroll
      for (int dt = 0; dt < 3; ++dt) {
        int d = dt * 32 + lr;
        int sw = ((d & 7) ^ ((d >> 3) & 7)) << 3;
        half8 vf = *(const half8*)&VF[bi][d * 64 + ((kstep * 16 + hi * 8) ^ sw)];
        oa[dt] = __builtin_amdgcn_mfma_f32_32x32x16_f16(pa.h8, vf, oa[dt], 0, 0, 0);
      }
      lacc = __builtin_amdgcn_mfma_f32_32x32x16_f16(pa.h8, vones, lacc, 0, 0, 0);
    }

    // --- T14 tail: V scatter-write for tile+1 (vmcnt wait hidden by compute)
    if (tile + 1 < 16) writeV(bi ^ 1);
  }

  // --- epilogue: O /= (l * sqrt(768)); l is lane-local in lacc (same row map)
  size_t rbase = (size_t)(b * 1024 + qt * 128 + w * 32) * 768 + h * 96;
#pragma unroll
  for (int r = 0; r < 16; ++r) {
    int q = (r & 3) + 8 * (r >> 2) + 4 * hi;
    float ivr = 1.0f / (lacc[r] * 27.712812921102035f);
#pragma unroll
    for (int dt = 0; dt < 3; ++dt)
      Oh[rbase + (size_t)q * 768 + dt * 32 + lr] = (_Float16)(oa[dt][r] * ivr);
  }
}

// ---------------- launch ----------------

extern "C" void kernel_launch(void* const* d_in, const int* in_sizes, int n_in,
                              void* d_out, int out_size, void* d_ws, size_t ws_size,
                              hipStream_t stream) {
  const float* x  = (const float*)d_in[0];
  const float* Wq = (const float*)d_in[1];
  const float* bq = (const float*)d_in[2];
  const float* Wk = (const float*)d_in[3];
  const float* bk = (const float*)d_in[4];
  const float* Wv = (const float*)d_in[5];
  const float* bv = (const float*)d_in[6];
  const float* Wo = (const float*)d_in[7];
  const float* bo = (const float*)d_in[8];
  float* out = (float*)d_out;

  char* ws = (char*)d_ws;
  _Float16* WT   = (_Float16*)(ws);                // 4,718,592 B
  float*    bias = (float*)(ws + 4718592);         // 9,216 B (padded to 32K)
  _Float16* xh   = (_Float16*)(ws + 4751360);      // 25,165,824 B
  _Float16* QKV  = (_Float16*)(ws + 29917184);     // 75,497,472 B
  _Float16* Oh   = (_Float16*)(ws + 105414656);    // 25,165,824 B  (total ~130.6 MB)

  conv_x_kernel<<<6144, 256, 0, stream>>>(x, xh);
  transpose_cvt_kernel<<<dim3(24, 24, 4), dim3(32, 8), 0, stream>>>(Wq, Wk, Wv, Wo, WT);
  conv_bias_kernel<<<9, 256, 0, stream>>>(bq, bk, bv, bias);

  // QKV: M=16384, N=2304, K=768 -> grid 128*18 = 2304 (3 exact rounds of 768)
  gemm_nt_kernel<1><<<2304, 256, 0, stream>>>(xh, WT, bias, QKV, 16384, 2304, 768, 2304);

  attn_kernel<<<1024, 256, 0, stream>>>(QKV, Oh);

  // out-proj: M=16384, N=768, K=768 -> grid 128*6 = 768 (1 exact round)
  gemm_nt_kernel<0><<<768, 256, 0, stream>>>(Oh, WT + (size_t)2304 * 768, bo, out,
                                             16384, 768, 768, 768);
}

// Round 12
// 227.370 us; speedup vs baseline: 1.3963x; 1.0232x over previous
//
#include <hip/hip_runtime.h>

// MultiHeadAttention B=16 N=1024 E=768 H=8 D=96 — fp16 MFMA pipeline.
// ws layout (130.6 MB total):
//   WT   [3072][768] fp16 : rows 0-2303 = (Wq|Wk|Wv)^T, rows 2304-3071 = Wo^T
//   (gap: 32K, former bias buffer — bias select now fused into GEMM epilogue)
//   xh   [16384][768] fp16
//   QKV  [16384][2304] fp16 (cols: 0-767 Q, 768-1535 K, 1536-2303 V; head h at h*96)
//   Oh   [16384][768] fp16 (attention output, pre-projection)

typedef _Float16 half8 __attribute__((ext_vector_type(8)));
typedef __fp16 fp16x2 __attribute__((ext_vector_type(2)));
typedef float f32x4 __attribute__((ext_vector_type(4)));
typedef float f32x16 __attribute__((ext_vector_type(16)));

__device__ __forceinline__ void gload_lds16(const void* g, void* l) {
  __builtin_amdgcn_global_load_lds((const __attribute__((address_space(1))) void*)g,
                                   (__attribute__((address_space(3))) void*)l, 16, 0, 0);
}

// ---------------- converts ----------------

__global__ __launch_bounds__(256) void conv_x_kernel(const float* __restrict__ x,
                                                     _Float16* __restrict__ xh) {
  long i = ((long)blockIdx.x * 256 + threadIdx.x) * 8;
  float4 a = *(const float4*)(x + i);
  float4 b = *(const float4*)(x + i + 4);
  half8 o;
  o[0] = (_Float16)a.x; o[1] = (_Float16)a.y; o[2] = (_Float16)a.z; o[3] = (_Float16)a.w;
  o[4] = (_Float16)b.x; o[5] = (_Float16)b.y; o[6] = (_Float16)b.z; o[7] = (_Float16)b.w;
  *(half8*)(xh + i) = o;
}

__global__ __launch_bounds__(256) void transpose_cvt_kernel(
    const float* __restrict__ W0, const float* __restrict__ W1,
    const float* __restrict__ W2, const float* __restrict__ W3,
    _Float16* __restrict__ WT) {
  __shared__ float tile[32][33];
  int z = blockIdx.z;
  const float* W = (z == 0) ? W0 : (z == 1) ? W1 : (z == 2) ? W2 : W3;
  int k0 = blockIdx.y * 32, n0 = blockIdx.x * 32;
  int tx = threadIdx.x, ty = threadIdx.y;
#pragma unroll
  for (int j = ty; j < 32; j += 8)
    tile[j][tx] = W[(size_t)(k0 + j) * 768 + n0 + tx];
  __syncthreads();
  _Float16* dst = WT + (size_t)z * 768 * 768;
#pragma unroll
  for (int j = ty; j < 32; j += 8)
    dst[(size_t)(n0 + j) * 768 + k0 + tx] = (_Float16)tile[tx][j];
}

// ---------------- GEMM: C[M][ldc] = A[M][K] * Bt[N][K]^T + bias ----------------
// m97 structure upgraded to BK=64: 128x128 tile, 4 waves, global_load_lds w=16,
// 2 barriers per K-step (12 steps at K=768 — half the barrier drains of BK=32).
// BK=64 rows are 128B -> seg-XOR swizzle (seg ^= row&7, R5-proven pair) on the
// pre-swizzled global source AND the ds_read index (both-sides rule).
// Bias: 3-way select over (b0|b1|b2) fused in epilogue (col/768 partitions).

template <int OUT_F16>
__global__ __launch_bounds__(256) void gemm_nt_kernel(
    const _Float16* __restrict__ A, const _Float16* __restrict__ Bt,
    const float* __restrict__ b0, const float* __restrict__ b1,
    const float* __restrict__ b2, void* __restrict__ C,
    int M, int N, int K, int ldc) {
  __shared__ _Float16 As[128 * 64];
  __shared__ _Float16 Bs[128 * 64];
  int nbx = N >> 7;
  int nwg = gridDim.x;
  int wg = blockIdx.x;
  int cpx = nwg >> 3;                       // nwg % 8 == 0 guaranteed by launch
  int swz = (wg & 7) * cpx + (wg >> 3);     // XCD-aware bijective swizzle
  int bx = swz % nbx, by = swz / nbx;
  int m0 = by * 128, n0 = bx * 128;
  int t = threadIdx.x, l = t & 63, w = t >> 6;
  int lg = l >> 4, lr = l & 15;
  int wr = w >> 1, wc = w & 1;
  f32x4 acc[4][4] = {};

  // staging: slot s = j*256+t -> row = s>>3 (0..127), seg = s&7 (8 x 16B = 64 cols)
  int srow[4], ssc[4];
#pragma unroll
  for (int j = 0; j < 4; ++j) {
    int s = j * 256 + t;
    srow[j] = s >> 3;
    ssc[j] = ((s & 7) ^ (srow[j] & 7)) * 8;   // pre-swizzled source column (elems)
  }

  for (int k0 = 0; k0 < K; k0 += 64) {
    __syncthreads();  // previous compute done before overwrite
#pragma unroll
    for (int j = 0; j < 4; ++j)
      gload_lds16(A + (size_t)(m0 + srow[j]) * K + k0 + ssc[j], &As[(j * 256 + t) * 8]);
#pragma unroll
    for (int j = 0; j < 4; ++j)
      gload_lds16(Bt + (size_t)(n0 + srow[j]) * K + k0 + ssc[j], &Bs[(j * 256 + t) * 8]);
    __syncthreads();  // drains vmcnt -> tiles ready

#pragma unroll
    for (int kk = 0; kk < 2; ++kk) {
      half8 af[4], bf[4];
#pragma unroll
      for (int r = 0; r < 4; ++r) {
        int row = wr * 64 + r * 16 + lr;
        af[r] = *(const half8*)&As[row * 64 + (((kk * 4 + lg) ^ (row & 7)) * 8)];
      }
#pragma unroll
      for (int c = 0; c < 4; ++c) {
        int row = wc * 64 + c * 16 + lr;
        bf[c] = *(const half8*)&Bs[row * 64 + (((kk * 4 + lg) ^ (row & 7)) * 8)];
      }
#pragma unroll
      for (int r = 0; r < 4; ++r)
#pragma unroll
        for (int c = 0; c < 4; ++c)
          acc[r][c] = __builtin_amdgcn_mfma_f32_16x16x32_f16(af[r], bf[c], acc[r][c], 0, 0, 0);
    }
  }

#pragma unroll
  for (int r = 0; r < 4; ++r)
#pragma unroll
    for (int c = 0; c < 4; ++c) {
      int col = n0 + wc * 64 + c * 16 + lr;
      float bb = (col < 768) ? b0[col] : (col < 1536) ? b1[col - 768] : b2[col - 1536];
#pragma unroll
      for (int i = 0; i < 4; ++i) {
        int row = m0 + wr * 64 + r * 16 + lg * 4 + i;  // D: col=lane&15, row=4*(lane>>4)+i
        float v = acc[r][c][i] + bb;
        if (OUT_F16)
          ((_Float16*)C)[(size_t)row * ldc + col] = (_Float16)v;
        else
          ((float*)C)[(size_t)row * ldc + col] = v;
      }
    }
}

// ---------------- flash attention: 32x32 MFMA, in-register P (R11, unchanged) ----

__global__ __launch_bounds__(256, 2) void attn_kernel(const _Float16* __restrict__ QKV,
                                                      _Float16* __restrict__ Oh) {
  int hw = blockIdx.x;
  int lin = (hw & 7) * 128 + (hw >> 3);   // XCD-chunked
  int bh = lin >> 3, qt = lin & 7;
  int b = bh >> 3, h = bh & 7;
  int t = threadIdx.x, w = t >> 6, l = t & 63;
  int lr = l & 31, hi = l >> 5;

  __shared__ __align__(16) char KF[2][12288];
  __shared__ __align__(16) _Float16 VF[2][96 * 64];

  const _Float16* Qb = QKV + (size_t)b * 1024 * 2304 + h * 96;
  const _Float16* Kb = Qb + 768;
  const _Float16* Vb = Qb + 1536;

  half8 qf[6];
  {
    int qrow = qt * 128 + w * 32 + lr;
    const _Float16 s = (_Float16)1.4426950408889634f;  // LOG2E folded into Q
#pragma unroll
    for (int c = 0; c < 6; ++c) {
      qf[c] = *(const half8*)&Qb[(size_t)qrow * 2304 + c * 16 + hi * 8];
#pragma unroll
      for (int e = 0; e < 8; ++e) qf[c][e] = qf[c][e] * s;
    }
  }

  int ks_src[3], ks_dst[3];
#pragma unroll
  for (int j = 0; j < 3; ++j) {
    int s = j * 256 + t;
    int f = s >> 6, lane = s & 63;
    int sb = f / 6, c = f - sb * 6;
    ks_src[j] = (sb * 32 + (lane & 31)) * 2304 + c * 16 + ((lane >> 5) & 1) * 8;
    ks_dst[j] = s * 16;
  }
  bool vact[2];
  int v_src[2], v_dst[2][8];
#pragma unroll
  for (int j = 0; j < 2; ++j) {
    int u = j * 256 + t;
    vact[j] = u < 384;
    int kvp = u / 12, mm = u % 12;
    v_src[j] = 2 * kvp * 2304 + mm * 8;
#pragma unroll
    for (int e = 0; e < 8; ++e) {
      int d = mm * 8 + e;
      int sw = ((d & 7) ^ ((d >> 3) & 7)) << 3;
      v_dst[j][e] = d * 64 + ((2 * kvp) ^ sw);
    }
  }

  auto stage_K = [&](int kv0, int bi) {
    size_t goff = (size_t)kv0 * 2304;
#pragma unroll
    for (int j = 0; j < 3; ++j)
      gload_lds16(Kb + goff + ks_src[j], &KF[bi][ks_dst[j]]);
  };

  half8 vr0[2], vr1[2];                   // in-flight V tile (T14 split)
  auto loadV = [&](int kv0) {
    size_t goff = (size_t)kv0 * 2304;
#pragma unroll
    for (int j = 0; j < 2; ++j)
      if (vact[j]) {
        const _Float16* vp = Vb + goff + v_src[j];
        vr0[j] = *(const half8*)vp;
        vr1[j] = *(const half8*)(vp + 2304);
      }
  };
  auto writeV = [&](int bi) {
#pragma unroll
    for (int j = 0; j < 2; ++j)
      if (vact[j]) {
#pragma unroll
        for (int e = 0; e < 8; ++e) {
          union { _Float16 h2[2]; unsigned u32; } pk;
          pk.h2[0] = vr0[j][e]; pk.h2[1] = vr1[j][e];
          *(unsigned*)&VF[bi][v_dst[j][e]] = pk.u32;
        }
      }
  };

  half8 vones;
#pragma unroll
  for (int e = 0; e < 8; ++e) vones[e] = (_Float16)1.0f;

  float m_run = -3.0e38f;
  f32x16 oa[3] = {};
  f32x16 lacc = {};

  stage_K(0, 0);
  loadV(0);
  writeV(0);

  for (int tile = 0; tile < 16; ++tile) {
    int bi = tile & 1;
    __syncthreads();
    if (tile + 1 < 16) {
      stage_K((tile + 1) * 64, bi ^ 1);
      loadV((tile + 1) * 64);
      __builtin_amdgcn_sched_barrier(0);
    }

    f32x16 sA[2] = {};
#pragma unroll
    for (int sb = 0; sb < 2; ++sb)
#pragma unroll
      for (int c = 0; c < 6; ++c) {
        half8 kf = *(const half8*)(KF[bi] + (sb * 6 + c) * 1024 + l * 16);
        sA[sb] = __builtin_amdgcn_mfma_f32_32x32x16_f16(kf, qf[c], sA[sb], 0, 0, 0);
      }

    float tmax = -3.0e38f;
#pragma unroll
    for (int sb = 0; sb < 2; ++sb)
#pragma unroll
      for (int r = 0; r < 16; ++r) tmax = fmaxf(tmax, sA[sb][r]);
    tmax = fmaxf(tmax, __shfl_xor(tmax, 32, 64));

    if (!__all(tmax <= m_run + 11.5f)) {
      float m_new = fmaxf(m_run, tmax);
      float scale = __builtin_exp2f(m_run - m_new);
#pragma unroll
      for (int r = 0; r < 16; ++r) {
        float sr = __shfl(scale, (r & 3) + 8 * (r >> 2) + 4 * hi, 64);
        oa[0][r] *= sr; oa[1][r] *= sr; oa[2][r] *= sr;
        lacc[r] *= sr;
      }
      m_run = m_new;
    }

    unsigned keep[8], send[8];
#pragma unroll
    for (int sb = 0; sb < 2; ++sb) {
      float e[16];
#pragma unroll
      for (int r = 0; r < 16; ++r) e[r] = __builtin_exp2f(sA[sb][r] - m_run);
      unsigned w32[8];
#pragma unroll
      for (int p = 0; p < 4; ++p)
#pragma unroll
        for (int m = 0; m < 2; ++m) {
          union { fp16x2 h2; unsigned u; } pk;
          pk.h2 = __builtin_amdgcn_cvt_pkrtz(e[4 * p + 2 * m], e[4 * p + 2 * m + 1]);
          w32[p * 2 + m] = pk.u;
        }
#pragma unroll
      for (int kb = 0; kb < 2; ++kb)
#pragma unroll
        for (int m = 0; m < 2; ++m) {
          keep[sb * 4 + kb * 2 + m] = hi ? w32[(2 * kb + 1) * 2 + m] : w32[(2 * kb) * 2 + m];
          send[sb * 4 + kb * 2 + m] = hi ? w32[(2 * kb) * 2 + m] : w32[(2 * kb + 1) * 2 + m];
        }
    }

    unsigned recv[8];
#pragma unroll
    for (int i = 0; i < 8; ++i) recv[i] = __shfl_xor(send[i], 32, 64);

#pragma unroll
    for (int kstep = 0; kstep < 4; ++kstep) {
      int base = (kstep >> 1) * 4 + (kstep & 1) * 2;
      union { unsigned u[4]; half8 h8; } pa;
      pa.u[0] = hi ? recv[base + 0] : keep[base + 0];
      pa.u[1] = hi ? recv[base + 1] : keep[base + 1];
      pa.u[2] = hi ? keep[base + 0] : recv[base + 0];
      pa.u[3] = hi ? keep[base + 1] : recv[base + 1];
#pragma unroll
      for (int dt = 0; dt < 3; ++dt) {
        int d = dt * 32 + lr;
        int sw = ((d & 7) ^ ((d >> 3) & 7)) << 3;
        half8 vf = *(const half8*)&VF[bi][d * 64 + ((kstep * 16 + hi * 8) ^ sw)];
        oa[dt] = __builtin_amdgcn_mfma_f32_32x32x16_f16(pa.h8, vf, oa[dt], 0, 0, 0);
      }
      lacc = __builtin_amdgcn_mfma_f32_32x32x16_f16(pa.h8, vones, lacc, 0, 0, 0);
    }

    if (tile + 1 < 16) writeV(bi ^ 1);
  }

  size_t rbase = (size_t)(b * 1024 + qt * 128 + w * 32) * 768 + h * 96;
#pragma unroll
  for (int r = 0; r < 16; ++r) {
    int q = (r & 3) + 8 * (r >> 2) + 4 * hi;
    float ivr = 1.0f / (lacc[r] * 27.712812921102035f);
#pragma unroll
    for (int dt = 0; dt < 3; ++dt)
      Oh[rbase + (size_t)q * 768 + dt * 32 + lr] = (_Float16)(oa[dt][r] * ivr);
  }
}

// ---------------- launch ----------------

extern "C" void kernel_launch(void* const* d_in, const int* in_sizes, int n_in,
                              void* d_out, int out_size, void* d_ws, size_t ws_size,
                              hipStream_t stream) {
  const float* x  = (const float*)d_in[0];
  const float* Wq = (const float*)d_in[1];
  const float* bq = (const float*)d_in[2];
  const float* Wk = (const float*)d_in[3];
  const float* bk = (const float*)d_in[4];
  const float* Wv = (const float*)d_in[5];
  const float* bv = (const float*)d_in[6];
  const float* Wo = (const float*)d_in[7];
  const float* bo = (const float*)d_in[8];
  float* out = (float*)d_out;

  char* ws = (char*)d_ws;
  _Float16* WT   = (_Float16*)(ws);                // 4,718,592 B
  _Float16* xh   = (_Float16*)(ws + 4751360);      // 25,165,824 B
  _Float16* QKV  = (_Float16*)(ws + 29917184);     // 75,497,472 B
  _Float16* Oh   = (_Float16*)(ws + 105414656);    // 25,165,824 B  (total ~130.6 MB)

  conv_x_kernel<<<6144, 256, 0, stream>>>(x, xh);
  transpose_cvt_kernel<<<dim3(24, 24, 4), dim3(32, 8), 0, stream>>>(Wq, Wk, Wv, Wo, WT);

  // QKV: M=16384, N=2304, K=768 -> grid 128*18 = 2304 (3 exact rounds of 768)
  gemm_nt_kernel<1><<<2304, 256, 0, stream>>>(xh, WT, bq, bk, bv, QKV,
                                              16384, 2304, 768, 2304);

  attn_kernel<<<1024, 256, 0, stream>>>(QKV, Oh);

  // out-proj: M=16384, N=768, K=768 -> grid 128*6 = 768 (1 exact round)
  gemm_nt_kernel<0><<<768, 256, 0, stream>>>(Oh, WT + (size_t)2304 * 768, bo, bo, bo, out,
                                             16384, 768, 768, 768);
}